// Round 1
// baseline (547.629 us; speedup 1.0000x reference)
//
#include <hip/hip_runtime.h>

#define THREADS 512
#define WPB 8          // windows per block
#define NWIN 16384
#define NBLK (NWIN / WPB)

typedef short bf16x8 __attribute__((ext_vector_type(8)));
typedef float f32x4 __attribute__((ext_vector_type(4)));

__device__ __forceinline__ unsigned short f2bf(float x) {
    unsigned u = __float_as_uint(x);
    u += 0x7fffu + ((u >> 16) & 1u);     // RNE
    return (unsigned short)(u >> 16);
}
__device__ __forceinline__ float bf2f(unsigned short b) {
    return __uint_as_float(((unsigned)b) << 16);
}

// LDS pitches (elements) — chosen so row strides are not multiples of 128B
#define XP 136   // xs/qs/kx/aos pitch (bf16)
#define VP 72    // vt pitch (bf16)
#define PP 40    // ps pitch (bf16)
#define MP 64    // maskS pitch (f32)
#define BP 64    // biasS pitch (bf16)

__global__ __launch_bounds__(THREADS, 2)
void winattn_kernel(const float* __restrict__ x, const float* __restrict__ mask,
                    const float* __restrict__ qkv_w, const float* __restrict__ qkv_b,
                    const float* __restrict__ proj_w, const float* __restrict__ proj_b,
                    const float* __restrict__ bias_table, const int* __restrict__ rel_index,
                    float* __restrict__ out)
{
    // 146,176 bytes total (< 160 KiB/CU on gfx950)
    __shared__ __align__(16) unsigned short xs[64 * XP];     // x window, bf16 [tok][dim]
    __shared__ __align__(16) unsigned short qs[64 * XP];     // q (scaled)  [tok][dim]
    __shared__ __align__(16) unsigned short kx[64 * XP];     // k           [tok][dim]
    __shared__ __align__(16) unsigned short vt[128 * VP];    // v transposed [dim][tok]
    __shared__ __align__(16) unsigned short aos[64 * XP];    // attn out    [tok][dim]
    __shared__ __align__(16) unsigned short ps[8 * 32 * PP]; // per-wave P  [qtl][ktl]
    __shared__ __align__(16) float maskS[49 * MP];           // mask window [qt][kt]
    __shared__ __align__(16) unsigned short biasS[4 * 49 * BP]; // gathered rel bias

    const int tid  = threadIdx.x;
    const int wave = tid >> 6;
    const int lane = tid & 63;
    const int lg   = lane >> 4;
    const int l16  = lane & 15;

    // ---------------- persistent weight fragments (once per block) ----------------
    bf16x8 wB[3][4];      // qkv_w: wave owns N-cols [wave*48, wave*48+48)
    float  qb[3];
#pragma unroll
    for (int nt = 0; nt < 3; ++nt) {
        const int col = (wave * 3 + nt) * 16 + l16;          // qkv output column
        const float s = (col < 128) ? 0.17677669529663689f : 1.0f;  // fold q*SCALE
        const float* wp = qkv_w + (size_t)col * 128;
#pragma unroll
        for (int ks = 0; ks < 4; ++ks) {
            const float* p = wp + ks * 32 + lg * 8;
            bf16x8 f;
#pragma unroll
            for (int j = 0; j < 8; ++j) f[j] = (short)f2bf(p[j] * s);
            wB[nt][ks] = f;
        }
        qb[nt] = qkv_b[col] * s;
    }
    bf16x8 wP[4];         // proj_w rows [wave*16, wave*16+16) as A-fragments
    {
        const float* pp = proj_w + (size_t)(wave * 16 + l16) * 128;
#pragma unroll
        for (int ks = 0; ks < 4; ++ks) {
            const float* p = pp + ks * 32 + lg * 8;
            bf16x8 f;
#pragma unroll
            for (int j = 0; j < 8; ++j) f[j] = (short)f2bf(p[j]);
            wP[ks] = f;
        }
    }
    const float4 pb = *(const float4*)(proj_b + wave * 16 + lg * 4);

    const int win0 = blockIdx.x * WPB;

    // ---------------- prologue: stage window 0, bias gather, zero pads ----------------
#pragma unroll
    for (int it = 0; it < 4; ++it) {
        int e = it * 2048 + tid * 4;
        if (e < 6272) {
            float4 v = *(const float4*)(x + (size_t)win0 * 6272 + e);
            ushort4 u; u.x = f2bf(v.x); u.y = f2bf(v.y); u.z = f2bf(v.z); u.w = f2bf(v.w);
            *(ushort4*)&xs[(e >> 7) * XP + (e & 127)] = u;
        }
    }
    for (int i = 49 * XP + tid; i < 64 * XP; i += THREADS) xs[i] = 0;  // pad rows stay 0
    {
        const float* mp0 = mask + (size_t)(win0 & 1023) * 2401;
        for (int e = tid; e < 2401; e += THREADS)
            maskS[(e / 49) * MP + (e % 49)] = mp0[e];
    }
    for (int i = tid; i < 4 * 49 * 49; i += THREADS) {
        int h = i / 2401, rem = i - h * 2401;
        int qt = rem / 49, kt = rem - qt * 49;
        int idx = rel_index[qt * 49 + kt];
        biasS[(h * 49 + qt) * BP + kt] = f2bf(bias_table[idx * 4 + h]);
    }
    __syncthreads();

    for (int w = 0; w < WPB; ++w) {
        const int win = win0 + w;
        const bool pf = (w + 1 < WPB);

        // -------- prefetch next window's x and mask into registers --------
        float4 xr[4];
        float  mr[5];
        if (pf) {
            const float* xp1 = x + (size_t)(win + 1) * 6272;
#pragma unroll
            for (int it = 0; it < 4; ++it) {
                int e = it * 2048 + tid * 4;
                if (e < 6272) xr[it] = *(const float4*)(xp1 + e);
            }
            const float* mp1 = mask + (size_t)((win + 1) & 1023) * 2401;
#pragma unroll
            for (int it = 0; it < 5; ++it) {
                int e = it * THREADS + tid;
                if (e < 2401) mr[it] = mp1[e];
            }
        }

        // -------- QKV GEMM: qkv = x @ qkv_w^T (+b), q pre-scaled --------
        f32x4 acc[4][3];
#pragma unroll
        for (int mt = 0; mt < 4; ++mt)
#pragma unroll
            for (int nt = 0; nt < 3; ++nt) acc[mt][nt] = (f32x4){0.f, 0.f, 0.f, 0.f};
#pragma unroll
        for (int ks = 0; ks < 4; ++ks) {
            bf16x8 a[4];
#pragma unroll
            for (int mt = 0; mt < 4; ++mt)
                a[mt] = *(const bf16x8*)&xs[(mt * 16 + l16) * XP + ks * 32 + lg * 8];
#pragma unroll
            for (int nt = 0; nt < 3; ++nt)
#pragma unroll
                for (int mt = 0; mt < 4; ++mt)
                    acc[mt][nt] = __builtin_amdgcn_mfma_f32_16x16x32_bf16(
                        a[mt], wB[nt][ks], acc[mt][nt], 0, 0, 0);
        }
#pragma unroll
        for (int nt = 0; nt < 3; ++nt) {
            const int colg = (wave * 3 + nt) * 16 + l16;
#pragma unroll
            for (int mt = 0; mt < 4; ++mt) {
                const int row0 = mt * 16 + lg * 4;
                const float v0 = acc[mt][nt][0] + qb[nt];
                const float v1 = acc[mt][nt][1] + qb[nt];
                const float v2 = acc[mt][nt][2] + qb[nt];
                const float v3 = acc[mt][nt][3] + qb[nt];
                if (colg < 128) {
                    qs[(row0 + 0) * XP + colg] = f2bf(v0);
                    qs[(row0 + 1) * XP + colg] = f2bf(v1);
                    qs[(row0 + 2) * XP + colg] = f2bf(v2);
                    qs[(row0 + 3) * XP + colg] = f2bf(v3);
                } else if (colg < 256) {
                    const int c = colg - 128;
                    kx[(row0 + 0) * XP + c] = f2bf(v0);
                    kx[(row0 + 1) * XP + c] = f2bf(v1);
                    kx[(row0 + 2) * XP + c] = f2bf(v2);
                    kx[(row0 + 3) * XP + c] = f2bf(v3);
                } else {
                    ushort4 u; u.x = f2bf(v0); u.y = f2bf(v1); u.z = f2bf(v2); u.w = f2bf(v3);
                    *(ushort4*)&vt[(colg - 256) * VP + row0] = u;   // v transposed
                }
            }
        }
        __syncthreads();   // BAR1: qkv visible; xs free to overwrite

        if (pf) {   // store prefetched x for next window (xs dead until next QKV)
#pragma unroll
            for (int it = 0; it < 4; ++it) {
                int e = it * 2048 + tid * 4;
                if (e < 6272) {
                    ushort4 u; u.x = f2bf(xr[it].x); u.y = f2bf(xr[it].y);
                    u.z = f2bf(xr[it].z); u.w = f2bf(xr[it].w);
                    *(ushort4*)&xs[(e >> 7) * XP + (e & 127)] = u;
                }
            }
        }

        // -------- attention: wave = (head h, q-half mh). S' = K·Q^T --------
        const int h  = wave >> 1;
        const int mh = wave & 1;
        bf16x8 ak[4], bq[2];
#pragma unroll
        for (int mt = 0; mt < 4; ++mt)
            ak[mt] = *(const bf16x8*)&kx[(mt * 16 + l16) * XP + h * 32 + lg * 8];
#pragma unroll
        for (int nt = 0; nt < 2; ++nt)
            bq[nt] = *(const bf16x8*)&qs[((2 * mh + nt) * 16 + l16) * XP + h * 32 + lg * 8];
        f32x4 S[4][2];
#pragma unroll
        for (int mt = 0; mt < 4; ++mt)
#pragma unroll
            for (int nt = 0; nt < 2; ++nt)
                S[mt][nt] = __builtin_amdgcn_mfma_f32_16x16x32_bf16(
                    ak[mt], bq[nt], (f32x4){0.f, 0.f, 0.f, 0.f}, 0, 0, 0);

        float Pv[2][4][4];
#pragma unroll
        for (int nt = 0; nt < 2; ++nt) {
            const int qt = (2 * mh + nt) * 16 + l16;     // query token (C col)
            const bool qok = qt < 49;
            float lv[4][4];
#pragma unroll
            for (int mt = 0; mt < 4; ++mt) {
                const int kt0 = mt * 16 + lg * 4;        // key token base (C row)
                float b4[4] = {0.f, 0.f, 0.f, 0.f};
                float m4[4] = {0.f, 0.f, 0.f, 0.f};
                if (qok) {
                    ushort4 bu = *(const ushort4*)&biasS[(h * 49 + qt) * BP + kt0];
                    float4  mm = *(const float4*)&maskS[qt * MP + kt0];
                    b4[0] = bf2f(bu.x); b4[1] = bf2f(bu.y); b4[2] = bf2f(bu.z); b4[3] = bf2f(bu.w);
                    m4[0] = mm.x; m4[1] = mm.y; m4[2] = mm.z; m4[3] = mm.w;
                }
#pragma unroll
                for (int r = 0; r < 4; ++r) {
                    const int kt = kt0 + r;
                    lv[mt][r] = (qok && kt < 49) ? (S[mt][nt][r] + b4[r] + m4[r]) : -1e30f;
                }
            }
            float mx = -1e30f;
#pragma unroll
            for (int mt = 0; mt < 4; ++mt)
#pragma unroll
                for (int r = 0; r < 4; ++r) mx = fmaxf(mx, lv[mt][r]);
            mx = fmaxf(mx, __shfl_xor(mx, 16, 64));
            mx = fmaxf(mx, __shfl_xor(mx, 32, 64));
            float sum = 0.f;
#pragma unroll
            for (int mt = 0; mt < 4; ++mt)
#pragma unroll
                for (int r = 0; r < 4; ++r) {
                    const float p = exp2f((lv[mt][r] - mx) * 1.44269504f);
                    lv[mt][r] = p;
                    sum += p;
                }
            sum += __shfl_xor(sum, 16, 64);
            sum += __shfl_xor(sum, 32, 64);
            const float inv = 1.0f / sum;
#pragma unroll
            for (int mt = 0; mt < 4; ++mt)
#pragma unroll
                for (int r = 0; r < 4; ++r) Pv[nt][mt][r] = lv[mt][r] * inv;
        }

        // -------- PV: out_h = P @ V via per-wave LDS staging of P --------
        f32x4 O[2][2];
#pragma unroll
        for (int mq = 0; mq < 2; ++mq)
#pragma unroll
            for (int nt = 0; nt < 2; ++nt) O[mq][nt] = (f32x4){0.f, 0.f, 0.f, 0.f};
        unsigned short* psw = ps + wave * 32 * PP;
#pragma unroll
        for (int kh = 0; kh < 2; ++kh) {
#pragma unroll
            for (int nt = 0; nt < 2; ++nt)
#pragma unroll
                for (int mi = 0; mi < 2; ++mi) {
                    const int mt = 2 * kh + mi;
                    ushort4 u;
                    u.x = f2bf(Pv[nt][mt][0]); u.y = f2bf(Pv[nt][mt][1]);
                    u.z = f2bf(Pv[nt][mt][2]); u.w = f2bf(Pv[nt][mt][3]);
                    *(ushort4*)&psw[(nt * 16 + l16) * PP + mi * 16 + lg * 4] = u;
                }
            bf16x8 pa[2], bv[2];
#pragma unroll
            for (int mq = 0; mq < 2; ++mq)
                pa[mq] = *(const bf16x8*)&psw[(mq * 16 + l16) * PP + lg * 8];
#pragma unroll
            for (int nt = 0; nt < 2; ++nt)
                bv[nt] = *(const bf16x8*)&vt[(h * 32 + nt * 16 + l16) * VP + kh * 32 + lg * 8];
#pragma unroll
            for (int mq = 0; mq < 2; ++mq)
#pragma unroll
                for (int nt = 0; nt < 2; ++nt)
                    O[mq][nt] = __builtin_amdgcn_mfma_f32_16x16x32_bf16(
                        pa[mq], bv[nt], O[mq][nt], 0, 0, 0);
        }
#pragma unroll
        for (int mq = 0; mq < 2; ++mq)
#pragma unroll
            for (int nt = 0; nt < 2; ++nt) {
                const int dim  = h * 32 + nt * 16 + l16;
                const int row0 = mh * 32 + mq * 16 + lg * 4;
                aos[(row0 + 0) * XP + dim] = f2bf(O[mq][nt][0]);
                aos[(row0 + 1) * XP + dim] = f2bf(O[mq][nt][1]);
                aos[(row0 + 2) * XP + dim] = f2bf(O[mq][nt][2]);
                aos[(row0 + 3) * XP + dim] = f2bf(O[mq][nt][3]);
            }
        __syncthreads();   // BAR2: aos visible; maskS free to overwrite

        if (pf) {
#pragma unroll
            for (int it = 0; it < 5; ++it) {
                int e = it * THREADS + tid;
                if (e < 2401) maskS[(e / 49) * MP + (e % 49)] = mr[it];
            }
        }

        // -------- proj: out^T = proj_w · aos^T, coalesced float4 store --------
        f32x4 pacc[4];
#pragma unroll
        for (int nt = 0; nt < 4; ++nt) pacc[nt] = (f32x4){0.f, 0.f, 0.f, 0.f};
#pragma unroll
        for (int ks = 0; ks < 4; ++ks) {
#pragma unroll
            for (int nt = 0; nt < 4; ++nt) {
                bf16x8 bfr = *(const bf16x8*)&aos[(nt * 16 + l16) * XP + ks * 32 + lg * 8];
                pacc[nt] = __builtin_amdgcn_mfma_f32_16x16x32_bf16(wP[ks], bfr, pacc[nt], 0, 0, 0);
            }
        }
#pragma unroll
        for (int nt = 0; nt < 4; ++nt) {
            const int tok = nt * 16 + l16;
            if (tok < 49) {
                float4 o;
                o.x = pacc[nt][0] + pb.x;
                o.y = pacc[nt][1] + pb.y;
                o.z = pacc[nt][2] + pb.z;
                o.w = pacc[nt][3] + pb.w;
                *(float4*)(out + ((size_t)win * 49 + tok) * 128 + wave * 16 + lg * 4) = o;
            }
        }
        __syncthreads();   // BAR3: loop end
    }
}

extern "C" void kernel_launch(void* const* d_in, const int* in_sizes, int n_in,
                              void* d_out, int out_size, void* d_ws, size_t ws_size,
                              hipStream_t stream) {
    const float* x          = (const float*)d_in[0];
    const float* mask       = (const float*)d_in[1];
    const float* qkv_w      = (const float*)d_in[2];
    const float* qkv_b      = (const float*)d_in[3];
    const float* proj_w     = (const float*)d_in[4];
    const float* proj_b     = (const float*)d_in[5];
    const float* bias_table = (const float*)d_in[6];
    const int*   rel_index  = (const int*)d_in[7];
    float* out = (float*)d_out;
    (void)in_sizes; (void)n_in; (void)d_ws; (void)ws_size; (void)out_size;

    winattn_kernel<<<dim3(NBLK), dim3(THREADS), 0, stream>>>(
        x, mask, qkv_w, qkv_b, proj_w, proj_b, bias_table, rel_index, out);
}